// Round 2
// baseline (994.838 us; speedup 1.0000x reference)
//
#include <hip/hip_runtime.h>

static constexpr int NB = 128;
static constexpr int NT = 256;
static constexpr int NV = 64;
static constexpr int NBT = NB * NT;       // 32768
static constexpr int NBTV = NBT * NV;     // 2097152

typedef __attribute__((ext_vector_type(8))) short short8;
typedef __attribute__((ext_vector_type(4))) float f32x4;

__device__ __forceinline__ unsigned short f2bf(float x) {
    unsigned int u = __float_as_uint(x);
    return (unsigned short)((u + 0x7FFFu + ((u >> 16) & 1u)) >> 16);
}
__device__ __forceinline__ float bf2f(unsigned short b) {
    return __uint_as_float(((unsigned int)b) << 16);
}
__device__ __forceinline__ float sigm(float x) { return 1.0f / (1.0f + expf(-x)); }

__device__ __forceinline__ short8 pack8(float4 a, float4 b) {
    short8 r;
    r[0] = (short)f2bf(a.x); r[1] = (short)f2bf(a.y); r[2] = (short)f2bf(a.z); r[3] = (short)f2bf(a.w);
    r[4] = (short)f2bf(b.x); r[5] = (short)f2bf(b.y); r[6] = (short)f2bf(b.z); r[7] = (short)f2bf(b.w);
    return r;
}

__device__ __forceinline__ void dot4(float4& acc, const float4 wv, const float4 xv) {
    acc.x = fmaf(wv.x, xv.x, acc.x);
    acc.y = fmaf(wv.y, xv.y, acc.y);
    acc.z = fmaf(wv.z, xv.z, acc.z);
    acc.w = fmaf(wv.w, xv.w, acc.w);
}

// ---------------- K0: weight conversion (W_feat -> bf16, diag table) ----------------
__global__ void k_conv(const float* __restrict__ Wf, unsigned short* __restrict__ wbf,
                       float* __restrict__ wdiag) {
    int i = blockIdx.x * 256 + threadIdx.x;
    if (i < NV * 32 * NV) wbf[i] = f2bf(Wf[i]);
    if (i < 2048) wdiag[i] = bf2f(f2bf(Wf[i * 64 + (i >> 5)]));
}

// ---------------- K1: per-(b,v) stats ----------------
__global__ void k_stats(const int* __restrict__ lengths, const float* __restrict__ values,
                        const float* __restrict__ masks, const float* __restrict__ minv,
                        const float* __restrict__ maxv, float* __restrict__ stats,
                        float* __restrict__ mmn_ws, float* __restrict__ nmeans_ws) {
    int b = blockIdx.x; int v = threadIdx.x;
    const float* vp = values + (size_t)b * NT * NV + v;
    const float* mp = masks + (size_t)b * NT * NV + v;
    float sv = 0.f, sq = 0.f, sm = 0.f;
    for (int t = 0; t < NT; t++) {
        float x = vp[t * NV]; float m = mp[t * NV];
        sv += x; sq += x * x; sm += m;
    }
    float mean = sv / sm;
    float var = (sq - 2.0f * mean * sv + (float)NT * mean * mean) / (sm - 1.0f);
    var = fmaxf(var, 0.0f);
    float sd = sqrtf(var);
    float lf = (float)lengths[b];
    float miss = 1.0f - sm / lf;
    float mn = minv[b * NV + v]; float mx = maxv[b * NV + v];
    float mm = fmaxf(mx - mn, 1e-8f);
    float* st = stats + b * 256;
    if (v == 0) st[0] = lf;
    st[1 + v] = mean; st[65 + v] = sd; st[129 + v] = miss;
    mmn_ws[b * NV + v] = mm;
    nmeans_ws[b * NV + v] = (mean - mn) / mm;
}

// ---------------- K2: forward-fill + decay + x_complete + gamma ----------------
__global__ void k_fill(const float* __restrict__ values, const float* __restrict__ masks,
                       const float* __restrict__ deltas, const float* __restrict__ minv,
                       const float* __restrict__ Wd, const float* __restrict__ bd,
                       const float* __restrict__ mmn_ws, const float* __restrict__ nmeans_ws,
                       float* __restrict__ xcomp, float* __restrict__ gam) {
    int b = blockIdx.x; int v = threadIdx.x;
    size_t base = (size_t)b * NT * NV + v;
    float mn = minv[b * NV + v];
    float mm = mmn_ws[b * NV + v];
    float nmean = nmeans_ws[b * NV + v];
    float wd = Wd[v * NV + v], bdv = bd[v];
    float xp = 0.f, nvprev = 0.f, mprev = 0.f;
    for (int t = 0; t < NT; t++) {
        size_t i = base + (size_t)t * NV;
        float val = values[i], m = masks[i], d = deltas[i];
        float nv = (val - mn) / mm;
        if (t == 0) xp = nv; else xp = mprev * nvprev + (1.0f - mprev) * xp;
        float g = expf(-fmaxf(fmaf(d, wd, bdv), 0.0f));
        float xd = g * xp + (1.0f - g) * nmean;
        float xc = m * nv + (1.0f - m) * xd;
        xcomp[i] = xc; gam[i] = g;
        mprev = m; nvprev = nv;
    }
}

// ---------------- K3: ctx MLP ----------------
__global__ void k_ctxmlp(const float* __restrict__ stats, const float* __restrict__ Wc1,
                         const float* __restrict__ bc1, const float* __restrict__ Wc2,
                         const float* __restrict__ bc2, float* __restrict__ ctx) {
    int b = blockIdx.x, tid = threadIdx.x;  // 64 threads
    __shared__ float lw[64 * 193];
    __shared__ float ss[193];
    __shared__ float h1[64];
    for (int i = tid; i < 64 * 193; i += 64) lw[i] = Wc1[i];
    ss[tid] = stats[b * 256 + tid];
    ss[64 + tid] = stats[b * 256 + 64 + tid];
    ss[128 + tid] = stats[b * 256 + 128 + tid];
    if (tid == 0) ss[192] = stats[b * 256 + 192];
    __syncthreads();
    float acc = bc1[tid];
    const float* w = lw + tid * 193;
    for (int k = 0; k < 193; k++) acc = fmaf(w[k], ss[k], acc);
    h1[tid] = fmaxf(acc, 0.f);
    __syncthreads();
    if (tid < 32) {
        float a = bc2[tid];
        const float* w2 = Wc2 + tid * 64;
        for (int k = 0; k < 64; k++) a = fmaf(w2[k], h1[k], a);
        ctx[b * 64 + tid] = a;
    }
}

// ---------------- K4: GRU (1 sample / block, weights in VGPRs) ----------------
__global__ __launch_bounds__(128, 1) void k_gru(
    const float* __restrict__ xcomp, const float* __restrict__ masks,
    const int* __restrict__ lengths, const float* __restrict__ Wih,
    const float* __restrict__ Whh, const float* __restrict__ bih,
    const float* __restrict__ bhh, float* __restrict__ ctx) {
    int b = blockIdx.x; int tid = threadIdx.x;  // 128 threads
    __shared__ __align__(16) float sx[128];
    __shared__ __align__(16) float sh[32];
    __shared__ float sA[96], sB[96];
    float4 wih[32]; float4 whh[8];
    float bi = 0.f, bh = 0.f;
    if (tid < 96) {
        const float4* w = (const float4*)(Wih + (size_t)tid * 128);
        #pragma unroll
        for (int q = 0; q < 32; q++) wih[q] = w[q];
        const float4* w2 = (const float4*)(Whh + (size_t)tid * 32);
        #pragma unroll
        for (int q = 0; q < 8; q++) whh[q] = w2[q];
        bi = bih[tid]; bh = bhh[tid];
    }
    if (tid < 32) sh[tid] = 0.0f;
    int len = lengths[b];
    float hn = 0.f;
    size_t rowbase = (size_t)b * NT * NV;
    float nx = (tid < NV) ? xcomp[rowbase + tid] : masks[rowbase + tid - NV];
    __syncthreads();
    for (int t = 0; t < NT; t++) {
        sx[tid] = nx;
        __syncthreads();
        if (t + 1 < NT) {
            size_t rb = rowbase + (size_t)(t + 1) * NV;
            nx = (tid < NV) ? xcomp[rb + tid] : masks[rb + tid - NV];
        }
        if (tid < 96) {
            const float4* sx4 = (const float4*)sx;
            const float4* sh4 = (const float4*)sh;
            float4 a = {0, 0, 0, 0};
            #pragma unroll
            for (int q = 0; q < 32; q++) dot4(a, wih[q], sx4[q]);
            float av = bi + a.x + a.y + a.z + a.w;
            float4 a2 = {0, 0, 0, 0};
            #pragma unroll
            for (int q = 0; q < 8; q++) dot4(a2, whh[q], sh4[q]);
            float bv = bh + a2.x + a2.y + a2.z + a2.w;
            sA[tid] = av; sB[tid] = bv;
        }
        __syncthreads();
        if (tid < 32) {
            float r = sigm(sA[tid] + sB[tid]);
            float z = sigm(sA[32 + tid] + sB[32 + tid]);
            float n = tanhf(sA[64 + tid] + r * sB[64 + tid]);
            float hold = sh[tid];
            float hnew = (1.0f - z) * n + z * hold;
            sh[tid] = hnew;
            if (t < len) hn = hnew;
        }
    }
    if (tid < 32) ctx[b * 64 + 32 + tid] = hn;
}

// ---------------- K5: hinit ----------------
__global__ void k_hinit(const float* __restrict__ ctx, const float* __restrict__ Wi,
                        const float* __restrict__ bi, float* __restrict__ hinit) {
    int b = blockIdx.x; int j = threadIdx.x;  // 128
    __shared__ __align__(16) float sc[64];
    if (j < 64) sc[j] = ctx[b * 64 + j];
    __syncthreads();
    const float4* w = (const float4*)(Wi + (size_t)j * 64);
    const float4* c4 = (const float4*)sc;
    float4 a = {0, 0, 0, 0};
    #pragma unroll
    for (int q = 0; q < 16; q++) dot4(a, w[q], c4[q]);
    hinit[b * 128 + j] = bi[j] + a.x + a.y + a.z + a.w;
}

// ---------------- K6: bidirectional LSTM (1 sample+dir / block) ----------------
__global__ __launch_bounds__(256, 1) void k_lstm(
    const float* __restrict__ xcomp, const float* __restrict__ masks,
    const float* __restrict__ ctx, const float* __restrict__ hinit,
    const float* __restrict__ Wihf, const float* __restrict__ Whhf,
    const float* __restrict__ bihf, const float* __restrict__ bhhf,
    const float* __restrict__ Wihb, const float* __restrict__ Whhb,
    const float* __restrict__ bihb, const float* __restrict__ bhhb,
    float* __restrict__ out0, float* __restrict__ out1) {
    int bx = blockIdx.x; int b = bx >> 1; int dir = bx & 1; int tid = threadIdx.x;
    const float* Wih = dir ? Wihb : Wihf; const float* Whh = dir ? Whhb : Whhf;
    const float* bih = dir ? bihb : bihf; const float* bhh = dir ? bhhb : bhhf;
    float* hall = dir ? out1 : out0;
    __shared__ __align__(16) float sctx[64];
    __shared__ __align__(16) float sx[128];
    __shared__ __align__(16) float sh[64];
    __shared__ float sg[256];
    if (tid < 64) sctx[tid] = ctx[b * 64 + tid];
    __syncthreads();
    float cterm = bih[tid] + bhh[tid];
    {
        const float4* wc = (const float4*)(Wih + (size_t)tid * 192 + 128);
        const float4* c4 = (const float4*)sctx;
        float4 a = {0, 0, 0, 0};
        #pragma unroll
        for (int q = 0; q < 16; q++) dot4(a, wc[q], c4[q]);
        cterm += a.x + a.y + a.z + a.w;
    }
    float4 wih[32], whh[16];
    {
        const float4* w = (const float4*)(Wih + (size_t)tid * 192);
        #pragma unroll
        for (int q = 0; q < 32; q++) wih[q] = w[q];
        const float4* w2 = (const float4*)(Whh + (size_t)tid * 64);
        #pragma unroll
        for (int q = 0; q < 16; q++) whh[q] = w2[q];
    }
    float c = 0.f;
    if (tid < 64) {
        float h0 = hinit[b * 128 + dir * 64 + tid];
        c = tanhf(h0);
        sh[tid] = h0;
        int t0 = dir ? (NT - 1) : 0;
        hall[((size_t)b * NT + t0) * NV + tid] = h0;
    }
    size_t rowbase = (size_t)b * NT * NV;
    float nx = 0.f;
    {
        int tin = dir ? (NT - 1) : 0;
        size_t rb = rowbase + (size_t)tin * NV;
        if (tid < 128) nx = (tid < 64) ? xcomp[rb + tid] : masks[rb + tid - 64];
    }
    __syncthreads();
    for (int s = 0; s < NT - 1; s++) {
        if (tid < 128) sx[tid] = nx;
        __syncthreads();
        if (s + 1 < NT - 1 && tid < 128) {
            int tin = dir ? (NT - 2 - s) : (s + 1);
            size_t rb = rowbase + (size_t)tin * NV;
            nx = (tid < 64) ? xcomp[rb + tid] : masks[rb + tid - 64];
        }
        {
            const float4* sx4 = (const float4*)sx;
            const float4* sh4 = (const float4*)sh;
            float4 a = {0, 0, 0, 0};
            #pragma unroll
            for (int q = 0; q < 32; q++) dot4(a, wih[q], sx4[q]);
            #pragma unroll
            for (int q = 0; q < 16; q++) dot4(a, whh[q], sh4[q]);
            sg[tid] = cterm + a.x + a.y + a.z + a.w;
        }
        __syncthreads();
        if (tid < 64) {
            float gi = sg[tid], gf = sg[64 + tid], gg = sg[128 + tid], go = sg[192 + tid];
            c = sigm(gf) * c + sigm(gi) * tanhf(gg);
            float hnew = sigm(go) * tanhf(c);
            sh[tid] = hnew;
            int tout = dir ? (NT - 2 - s) : (s + 1);
            hall[((size_t)b * NT + tout) * NV + tid] = hnew;
        }
    }
}

// ---------------- K_feat: fused per-feature MLP via bf16 MFMA ----------------
__global__ __launch_bounds__(256) void k_feat(
    const float* __restrict__ xcomp, const unsigned short* __restrict__ wbf,
    const float* __restrict__ wdiag, const float* __restrict__ bfeat,
    const float* __restrict__ Wnl1, const float* __restrict__ bnl1,
    const float* __restrict__ Wnl2, const float* __restrict__ bnl2,
    float* __restrict__ feat_out) {
    int wave = threadIdx.x >> 6; int lane = threadIdx.x & 63;
    int bt0 = blockIdx.x * 64 + wave * 16;
    int r = lane & 15, kc = lane >> 4;
    __shared__ __align__(16) unsigned short hb[4][16 * 32];
    __shared__ __align__(16) float ldsx[4][64 * 16];
    __shared__ __align__(16) float fl[4][16 * 65];
    unsigned short* hbw = hb[wave];
    float* lx = ldsx[wave];
    float* flw = fl[wave];

    // A-fragments: rows = bt0+r, k = kc*8 + i  (k-chunk mapping identical for A and B -> safe)
    short8 a0, a1;
    {
        const float* xr = xcomp + (size_t)(bt0 + r) * NV + kc * 8;
        float4 p0 = *(const float4*)(xr);
        float4 p1 = *(const float4*)(xr + 4);
        a0 = pack8(p0, p1);
        float4 p2 = *(const float4*)(xr + 32);
        float4 p3 = *(const float4*)(xr + 36);
        a1 = pack8(p2, p3);
    }
    // stage float(bf16(x)) tile transposed: lx[g*16 + row]
    {
        int gc0 = kc * 16;
        const float* xr2 = xcomp + (size_t)(bt0 + r) * NV + gc0;
        #pragma unroll
        for (int e = 0; e < 16; e += 4) {
            float4 p = *(const float4*)(xr2 + e);
            lx[(gc0 + e + 0) * 16 + r] = bf2f(f2bf(p.x));
            lx[(gc0 + e + 1) * 16 + r] = bf2f(f2bf(p.y));
            lx[(gc0 + e + 2) * 16 + r] = bf2f(f2bf(p.z));
            lx[(gc0 + e + 3) * 16 + r] = bf2f(f2bf(p.w));
        }
    }
    // W_nl1 B-fragments (loop invariant): B[k=h][n=h'] = W_nl1[h'][h]
    short8 wb0, wb1;
    {
        const float* w = Wnl1 + r * 32 + kc * 8;
        float4 q0 = *(const float4*)w, q1 = *(const float4*)(w + 4);
        wb0 = pack8(q0, q1);
        const float* w2 = Wnl1 + (16 + r) * 32 + kc * 8;
        float4 q2 = *(const float4*)w2, q3 = *(const float4*)(w2 + 4);
        wb1 = pack8(q2, q3);
    }
    float w2c0 = Wnl2[r], w2c1 = Wnl2[16 + r];
    float bn0 = bnl1[r], bn1 = bnl1[16 + r];
    float bn2 = bnl2[0];
    __builtin_amdgcn_wave_barrier();

    #pragma unroll 2
    for (int g = 0; g < 64; g++) {
        __builtin_amdgcn_wave_barrier();
        float xv[4];
        #pragma unroll
        for (int i = 0; i < 4; i++) xv[i] = lx[g * 16 + kc * 4 + i];
        float p[4] = {0.f, 0.f, 0.f, 0.f};
        #pragma unroll
        for (int f = 0; f < 2; f++) {
            int n0 = g * 32 + f * 16;
            const unsigned short* wrow = wbf + (size_t)(n0 + r) * 64;
            short8 b0 = *(const short8*)(wrow + kc * 8);
            short8 b1 = *(const short8*)(wrow + 32 + kc * 8);
            f32x4 acc = {0.f, 0.f, 0.f, 0.f};
            acc = __builtin_amdgcn_mfma_f32_16x16x32_bf16(a0, b0, acc, 0, 0, 0);
            acc = __builtin_amdgcn_mfma_f32_16x16x32_bf16(a1, b1, acc, 0, 0, 0);
            int n = n0 + r;
            float wd = wdiag[n], bs = bfeat[n];
            #pragma unroll
            for (int i = 0; i < 4; i++) {
                float h = acc[i] - xv[i] * wd + bs;   // remove v==g diagonal
                h = fmaxf(h, 0.0f);
                hbw[(kc * 4 + i) * 32 + f * 16 + r] = f2bf(h);
            }
        }
        __builtin_amdgcn_wave_barrier();
        // z = relu(hidden) @ W_nl1^T  (A' from LDS, same k-mapping as wb frags)
        short8 ah = *(const short8*)(hbw + r * 32 + kc * 8);
        f32x4 z0 = {0.f, 0.f, 0.f, 0.f}, z1 = {0.f, 0.f, 0.f, 0.f};
        z0 = __builtin_amdgcn_mfma_f32_16x16x32_bf16(ah, wb0, z0, 0, 0, 0);
        z1 = __builtin_amdgcn_mfma_f32_16x16x32_bf16(ah, wb1, z1, 0, 0, 0);
        #pragma unroll
        for (int i = 0; i < 4; i++) {
            float za = fmaxf(z0[i] + bn0, 0.0f);
            float zb = fmaxf(z1[i] + bn1, 0.0f);
            p[i] = fmaf(za, w2c0, fmaf(zb, w2c1, p[i]));
        }
        #pragma unroll
        for (int m = 1; m < 16; m <<= 1) {
            #pragma unroll
            for (int i = 0; i < 4; i++) p[i] += __shfl_xor(p[i], m, 64);
        }
        if (r == 0) {
            #pragma unroll
            for (int i = 0; i < 4; i++) flw[(kc * 4 + i) * 65 + g] = p[i] + bn2;
        }
    }
    __builtin_amdgcn_wave_barrier();
    #pragma unroll
    for (int q = 0; q < 16; q++)
        feat_out[(size_t)(bt0 + q) * NV + lane] = flw[q * 65 + lane];
}

// ---------------- K7: rnn_imp = h_cat @ W_ri^T + b_ri ----------------
__global__ void k_rnnimp(const float* __restrict__ out0, const float* __restrict__ out1,
                         const float* __restrict__ Wri, const float* __restrict__ bri,
                         float* __restrict__ rnnraw) {
    int bt0 = blockIdx.x * 4;
    int tid = threadIdx.x;
    int rr = tid >> 6, v = tid & 63;
    __shared__ __align__(16) float hc[4][128];
    hc[rr][v] = out0[(size_t)(bt0 + rr) * NV + v];
    hc[rr][64 + v] = out1[(size_t)(bt0 + rr) * NV + v];
    __syncthreads();
    const float4* w = (const float4*)(Wri + (size_t)v * 128);
    const float4* h4 = (const float4*)hc[rr];
    float4 a = {0, 0, 0, 0};
    #pragma unroll
    for (int q = 0; q < 32; q++) dot4(a, w[q], h4[q]);
    rnnraw[(size_t)(bt0 + rr) * NV + v] = bri[v] + a.x + a.y + a.z + a.w;
}

// ---------------- K8: beta fusion + scale + write all 3 outputs ----------------
__global__ void k_final(const float* __restrict__ rnnraw, const float* __restrict__ gam,
                        const float* __restrict__ masks, const float* __restrict__ Wfu,
                        const float* __restrict__ bfu, const float* __restrict__ mmn_ws,
                        const float* __restrict__ minv, float* __restrict__ out0,
                        float* __restrict__ out1, float* __restrict__ out2) {
    int bt0 = blockIdx.x * 4; int tid = threadIdx.x;
    int rr = tid >> 6, v = tid & 63;
    __shared__ __align__(16) float gm[4][128];
    size_t row = (size_t)(bt0 + rr) * NV;
    gm[rr][v] = gam[row + v];
    gm[rr][64 + v] = masks[row + v];
    __syncthreads();
    const float4* w = (const float4*)(Wfu + (size_t)v * 128);
    const float4* x4 = (const float4*)gm[rr];
    float4 a = {0, 0, 0, 0};
    #pragma unroll
    for (int q = 0; q < 32; q++) dot4(a, w[q], x4[q]);
    float beta = sigm(bfu[v] + a.x + a.y + a.z + a.w);
    size_t idx = row + v;
    float rn = rnnraw[idx];
    float ft = out2[idx];
    float fin = beta * ft + (1.0f - beta) * rn;
    int b = (bt0 + rr) >> 8;
    float mm = mmn_ws[b * NV + v], mn = minv[b * NV + v];
    out0[idx] = fmaf(rn, mm, mn);
    out1[idx] = fmaf(ft, mm, mn);
    out2[idx] = fmaf(fin, mm, mn);
}

extern "C" void kernel_launch(void* const* d_in, const int* in_sizes, int n_in,
                              void* d_out, int out_size, void* d_ws, size_t ws_size,
                              hipStream_t stream) {
    const int*   lengths  = (const int*)d_in[0];
    const float* values   = (const float*)d_in[1];
    const float* masks    = (const float*)d_in[2];
    const float* deltas   = (const float*)d_in[3];
    const float* min_vals = (const float*)d_in[4];
    const float* max_vals = (const float*)d_in[5];
    const float* W_decay  = (const float*)d_in[6];
    const float* b_decay  = (const float*)d_in[7];
    const float* W_feat   = (const float*)d_in[8];
    const float* b_feat   = (const float*)d_in[9];
    const float* W_nl1    = (const float*)d_in[10];
    const float* b_nl1    = (const float*)d_in[11];
    const float* W_nl2    = (const float*)d_in[12];
    const float* b_nl2    = (const float*)d_in[13];
    const float* Wc1      = (const float*)d_in[14];
    const float* bc1      = (const float*)d_in[15];
    const float* Wc2      = (const float*)d_in[16];
    const float* bc2      = (const float*)d_in[17];
    const float* W_ih_g   = (const float*)d_in[18];
    const float* W_hh_g   = (const float*)d_in[19];
    const float* b_ih_g   = (const float*)d_in[20];
    const float* b_hh_g   = (const float*)d_in[21];
    const float* W_init   = (const float*)d_in[22];
    const float* b_init   = (const float*)d_in[23];
    const float* W_ih_f   = (const float*)d_in[24];
    const float* W_hh_f   = (const float*)d_in[25];
    const float* b_ih_f   = (const float*)d_in[26];
    const float* b_hh_f   = (const float*)d_in[27];
    const float* W_ih_b   = (const float*)d_in[28];
    const float* W_hh_b   = (const float*)d_in[29];
    const float* b_ih_b   = (const float*)d_in[30];
    const float* b_hh_b   = (const float*)d_in[31];
    const float* W_ri     = (const float*)d_in[32];
    const float* b_ri     = (const float*)d_in[33];
    const float* W_fu     = (const float*)d_in[34];
    const float* b_fu     = (const float*)d_in[35];

    float* ws = (float*)d_ws;
    float* xcomp  = ws;                     // 2097152
    float* gam    = ws + 2097152;           // 2097152
    float* rnnraw = ws + 4194304;           // 2097152
    float* stats  = ws + 6291456;           // 32768
    float* mmn    = ws + 6324224;           // 8192
    float* nmeans = ws + 6332416;           // 8192
    float* ctx    = ws + 6340608;           // 8192
    float* hinit  = ws + 6348800;           // 16384
    unsigned short* wbf = (unsigned short*)(ws + 6365184);  // 131072 ushorts
    float* wdiag  = ws + 6430720;           // 2048  (total ~25.7 MB)

    float* out0 = (float*)d_out;
    float* out1 = out0 + NBTV;
    float* out2 = out0 + 2 * NBTV;

    k_conv<<<512, 256, 0, stream>>>(W_feat, wbf, wdiag);
    k_stats<<<NB, 64, 0, stream>>>(lengths, values, masks, min_vals, max_vals, stats, mmn, nmeans);
    k_fill<<<NB, 64, 0, stream>>>(values, masks, deltas, min_vals, W_decay, b_decay, mmn, nmeans, xcomp, gam);
    k_feat<<<NBT / 64, 256, 0, stream>>>(xcomp, wbf, wdiag, b_feat, W_nl1, b_nl1, W_nl2, b_nl2, out2);
    k_ctxmlp<<<NB, 64, 0, stream>>>(stats, Wc1, bc1, Wc2, bc2, ctx);
    k_gru<<<NB, 128, 0, stream>>>(xcomp, masks, lengths, W_ih_g, W_hh_g, b_ih_g, b_hh_g, ctx);
    k_hinit<<<NB, 128, 0, stream>>>(ctx, W_init, b_init, hinit);
    k_lstm<<<2 * NB, 256, 0, stream>>>(xcomp, masks, ctx, hinit,
                                       W_ih_f, W_hh_f, b_ih_f, b_hh_f,
                                       W_ih_b, W_hh_b, b_ih_b, b_hh_b, out0, out1);
    k_rnnimp<<<NBT / 4, 256, 0, stream>>>(out0, out1, W_ri, b_ri, rnnraw);
    k_final<<<NBT / 4, 256, 0, stream>>>(rnnraw, gam, masks, W_fu, b_fu, mmn, min_vals, out0, out1, out2);
}

// Round 3
// 780.424 us; speedup vs baseline: 1.2747x; 1.2747x over previous
//
#include <hip/hip_runtime.h>

static constexpr int NB = 128;
static constexpr int NT = 256;
static constexpr int NV = 64;
static constexpr int NBT = NB * NT;       // 32768
static constexpr int NBTV = NBT * NV;     // 2097152

typedef __attribute__((ext_vector_type(8))) short short8;
typedef __attribute__((ext_vector_type(4))) float f32x4;

__device__ __forceinline__ unsigned short f2bf(float x) {
    unsigned int u = __float_as_uint(x);
    return (unsigned short)((u + 0x7FFFu + ((u >> 16) & 1u)) >> 16);
}
__device__ __forceinline__ float bf2f(unsigned short b) {
    return __uint_as_float(((unsigned int)b) << 16);
}
__device__ __forceinline__ float sigm(float x) { return 1.0f / (1.0f + expf(-x)); }

__device__ __forceinline__ short8 pack8(float4 a, float4 b) {
    short8 r;
    r[0] = (short)f2bf(a.x); r[1] = (short)f2bf(a.y); r[2] = (short)f2bf(a.z); r[3] = (short)f2bf(a.w);
    r[4] = (short)f2bf(b.x); r[5] = (short)f2bf(b.y); r[6] = (short)f2bf(b.z); r[7] = (short)f2bf(b.w);
    return r;
}

__device__ __forceinline__ void dot4(float4& acc, const float4 wv, const float4 xv) {
    acc.x = fmaf(wv.x, xv.x, acc.x);
    acc.y = fmaf(wv.y, xv.y, acc.y);
    acc.z = fmaf(wv.z, xv.z, acc.z);
    acc.w = fmaf(wv.w, xv.w, acc.w);
}

// ---------------- K0: weight conversions to bf16 ----------------
__global__ void k_conv(const float* __restrict__ Wf, const float* __restrict__ Wihf,
                       const float* __restrict__ Wihb, const float* __restrict__ Wihg,
                       unsigned short* __restrict__ wbf, float* __restrict__ wdiag,
                       unsigned short* __restrict__ wgf, unsigned short* __restrict__ wgb,
                       unsigned short* __restrict__ wgg) {
    int i = blockIdx.x * 256 + threadIdx.x;
    if (i < NV * 32 * NV) wbf[i] = f2bf(Wf[i]);
    if (i < 2048) wdiag[i] = bf2f(f2bf(Wf[i * 64 + (i >> 5)]));
    if (i < 32768) {
        int n = i >> 7, k = i & 127;
        wgf[i] = f2bf(Wihf[n * 192 + k]);
        wgb[i] = f2bf(Wihb[n * 192 + k]);
    }
    if (i < 12288) wgg[i] = f2bf(Wihg[i]);
}

// ---------------- K1: per-(b,v) stats ----------------
__global__ void k_stats(const int* __restrict__ lengths, const float* __restrict__ values,
                        const float* __restrict__ masks, const float* __restrict__ minv,
                        const float* __restrict__ maxv, float* __restrict__ stats,
                        float* __restrict__ mmn_ws, float* __restrict__ nmeans_ws) {
    int b = blockIdx.x; int v = threadIdx.x;
    const float* vp = values + (size_t)b * NT * NV + v;
    const float* mp = masks + (size_t)b * NT * NV + v;
    float sv = 0.f, sq = 0.f, sm = 0.f;
    for (int t = 0; t < NT; t++) {
        float x = vp[t * NV]; float m = mp[t * NV];
        sv += x; sq += x * x; sm += m;
    }
    float mean = sv / sm;
    float var = (sq - 2.0f * mean * sv + (float)NT * mean * mean) / (sm - 1.0f);
    var = fmaxf(var, 0.0f);
    float sd = sqrtf(var);
    float lf = (float)lengths[b];
    float miss = 1.0f - sm / lf;
    float mn = minv[b * NV + v]; float mx = maxv[b * NV + v];
    float mm = fmaxf(mx - mn, 1e-8f);
    float* st = stats + b * 256;
    if (v == 0) st[0] = lf;
    st[1 + v] = mean; st[65 + v] = sd; st[129 + v] = miss;
    mmn_ws[b * NV + v] = mm;
    nmeans_ws[b * NV + v] = (mean - mn) / mm;
}

// ---------------- K2: forward-fill + decay + x_complete + gamma ----------------
__global__ void k_fill(const float* __restrict__ values, const float* __restrict__ masks,
                       const float* __restrict__ deltas, const float* __restrict__ minv,
                       const float* __restrict__ Wd, const float* __restrict__ bd,
                       const float* __restrict__ mmn_ws, const float* __restrict__ nmeans_ws,
                       float* __restrict__ xcomp, float* __restrict__ gam) {
    int b = blockIdx.x; int v = threadIdx.x;
    size_t base = (size_t)b * NT * NV + v;
    float mn = minv[b * NV + v];
    float mm = mmn_ws[b * NV + v];
    float nmean = nmeans_ws[b * NV + v];
    float wd = Wd[v * NV + v], bdv = bd[v];
    float xp = 0.f, nvprev = 0.f, mprev = 0.f;
    for (int t = 0; t < NT; t++) {
        size_t i = base + (size_t)t * NV;
        float val = values[i], m = masks[i], d = deltas[i];
        float nv = (val - mn) / mm;
        if (t == 0) xp = nv; else xp = mprev * nvprev + (1.0f - mprev) * xp;
        float g = expf(-fmaxf(fmaf(d, wd, bdv), 0.0f));
        float xd = g * xp + (1.0f - g) * nmean;
        float xc = m * nv + (1.0f - m) * xd;
        xcomp[i] = xc; gam[i] = g;
        mprev = m; nvprev = nv;
    }
}

// ---------------- K_gates: MFMA GEMM for all input-side gate projections ----------------
// gates_f/b[bt][256] = [x;m] @ Wih[:, :128]^T ; gates_g[bt][96] = [x;m] @ Wih_g^T
__global__ __launch_bounds__(256) void k_gates(
    const float* __restrict__ xcomp, const float* __restrict__ masks,
    const unsigned short* __restrict__ wgf, const unsigned short* __restrict__ wgb,
    const unsigned short* __restrict__ wgg,
    float* __restrict__ gf, float* __restrict__ gb, float* __restrict__ gg) {
    int wave = threadIdx.x >> 6, lane = threadIdx.x & 63;
    int bt0 = blockIdx.x * 64 + wave * 16;
    int r = lane & 15, kc = lane >> 4;
    const float* xr = xcomp + (size_t)(bt0 + r) * NV + kc * 8;
    const float* mr = masks + (size_t)(bt0 + r) * NV + kc * 8;
    short8 af0, af1, af2, af3;
    af0 = pack8(*(const float4*)(xr), *(const float4*)(xr + 4));
    af1 = pack8(*(const float4*)(xr + 32), *(const float4*)(xr + 36));
    af2 = pack8(*(const float4*)(mr), *(const float4*)(mr + 4));
    af3 = pack8(*(const float4*)(mr + 32), *(const float4*)(mr + 36));
    #pragma unroll 4
    for (int nt = 0; nt < 16; nt++) {
        const unsigned short* w = wgf + (size_t)(nt * 16 + r) * 128 + kc * 8;
        f32x4 acc = {0.f, 0.f, 0.f, 0.f};
        acc = __builtin_amdgcn_mfma_f32_16x16x32_bf16(af0, *(const short8*)(w), acc, 0, 0, 0);
        acc = __builtin_amdgcn_mfma_f32_16x16x32_bf16(af1, *(const short8*)(w + 32), acc, 0, 0, 0);
        acc = __builtin_amdgcn_mfma_f32_16x16x32_bf16(af2, *(const short8*)(w + 64), acc, 0, 0, 0);
        acc = __builtin_amdgcn_mfma_f32_16x16x32_bf16(af3, *(const short8*)(w + 96), acc, 0, 0, 0);
        #pragma unroll
        for (int i = 0; i < 4; i++)
            gf[(size_t)(bt0 + kc * 4 + i) * 256 + nt * 16 + r] = acc[i];
    }
    #pragma unroll 4
    for (int nt = 0; nt < 16; nt++) {
        const unsigned short* w = wgb + (size_t)(nt * 16 + r) * 128 + kc * 8;
        f32x4 acc = {0.f, 0.f, 0.f, 0.f};
        acc = __builtin_amdgcn_mfma_f32_16x16x32_bf16(af0, *(const short8*)(w), acc, 0, 0, 0);
        acc = __builtin_amdgcn_mfma_f32_16x16x32_bf16(af1, *(const short8*)(w + 32), acc, 0, 0, 0);
        acc = __builtin_amdgcn_mfma_f32_16x16x32_bf16(af2, *(const short8*)(w + 64), acc, 0, 0, 0);
        acc = __builtin_amdgcn_mfma_f32_16x16x32_bf16(af3, *(const short8*)(w + 96), acc, 0, 0, 0);
        #pragma unroll
        for (int i = 0; i < 4; i++)
            gb[(size_t)(bt0 + kc * 4 + i) * 256 + nt * 16 + r] = acc[i];
    }
    #pragma unroll 3
    for (int nt = 0; nt < 6; nt++) {
        const unsigned short* w = wgg + (size_t)(nt * 16 + r) * 128 + kc * 8;
        f32x4 acc = {0.f, 0.f, 0.f, 0.f};
        acc = __builtin_amdgcn_mfma_f32_16x16x32_bf16(af0, *(const short8*)(w), acc, 0, 0, 0);
        acc = __builtin_amdgcn_mfma_f32_16x16x32_bf16(af1, *(const short8*)(w + 32), acc, 0, 0, 0);
        acc = __builtin_amdgcn_mfma_f32_16x16x32_bf16(af2, *(const short8*)(w + 64), acc, 0, 0, 0);
        acc = __builtin_amdgcn_mfma_f32_16x16x32_bf16(af3, *(const short8*)(w + 96), acc, 0, 0, 0);
        #pragma unroll
        for (int i = 0; i < 4; i++)
            gg[(size_t)(bt0 + kc * 4 + i) * 96 + nt * 16 + r] = acc[i];
    }
}

// ---------------- K3: ctx MLP ----------------
__global__ void k_ctxmlp(const float* __restrict__ stats, const float* __restrict__ Wc1,
                         const float* __restrict__ bc1, const float* __restrict__ Wc2,
                         const float* __restrict__ bc2, float* __restrict__ ctx) {
    int b = blockIdx.x, tid = threadIdx.x;  // 64 threads
    __shared__ float lw[64 * 193];
    __shared__ float ss[193];
    __shared__ float h1[64];
    for (int i = tid; i < 64 * 193; i += 64) lw[i] = Wc1[i];
    ss[tid] = stats[b * 256 + tid];
    ss[64 + tid] = stats[b * 256 + 64 + tid];
    ss[128 + tid] = stats[b * 256 + 128 + tid];
    if (tid == 0) ss[192] = stats[b * 256 + 192];
    __syncthreads();
    float acc = bc1[tid];
    const float* w = lw + tid * 193;
    for (int k = 0; k < 193; k++) acc = fmaf(w[k], ss[k], acc);
    h1[tid] = fmaxf(acc, 0.f);
    __syncthreads();
    if (tid < 32) {
        float a = bc2[tid];
        const float* w2 = Wc2 + tid * 64;
        for (int k = 0; k < 64; k++) a = fmaf(w2[k], h1[k], a);
        ctx[b * 64 + tid] = a;
    }
}

// ---------------- K4: GRU (precomputed input gates, whh in VGPRs) ----------------
__global__ __launch_bounds__(128, 1) void k_gru(
    const float* __restrict__ gg, const int* __restrict__ lengths,
    const float* __restrict__ Whh, const float* __restrict__ bih,
    const float* __restrict__ bhh, float* __restrict__ ctx) {
    int b = blockIdx.x; int tid = threadIdx.x;  // 128 threads
    __shared__ __align__(16) float sh[32];
    __shared__ float sA[96], sB[96];
    float4 whh[8];
    float bi = 0.f, bh = 0.f;
    if (tid < 96) {
        const float4* w2 = (const float4*)(Whh + (size_t)tid * 32);
        #pragma unroll
        for (int q = 0; q < 8; q++) whh[q] = w2[q];
        bi = bih[tid]; bh = bhh[tid];
    }
    if (tid < 32) sh[tid] = 0.0f;
    int len = lengths[b];
    float hn = 0.f;
    const float* gbase = gg + (size_t)b * NT * 96;
    float gnext = (tid < 96) ? gbase[tid] : 0.f;
    __syncthreads();
    for (int t = 0; t < NT; t++) {
        float gcur = gnext;
        if (t + 1 < NT && tid < 96) gnext = gbase[(size_t)(t + 1) * 96 + tid];
        if (tid < 96) {
            const float4* sh4 = (const float4*)sh;
            float4 a2 = {0, 0, 0, 0};
            #pragma unroll
            for (int q = 0; q < 8; q++) dot4(a2, whh[q], sh4[q]);
            sA[tid] = bi + gcur;
            sB[tid] = bh + a2.x + a2.y + a2.z + a2.w;
        }
        __syncthreads();
        if (tid < 32) {
            float r = sigm(sA[tid] + sB[tid]);
            float z = sigm(sA[32 + tid] + sB[32 + tid]);
            float n = tanhf(sA[64 + tid] + r * sB[64 + tid]);
            float hold = sh[tid];
            float hnew = (1.0f - z) * n + z * hold;
            sh[tid] = hnew;
            if (t < len) hn = hnew;
        }
        __syncthreads();
    }
    if (tid < 32) ctx[b * 64 + 32 + tid] = hn;
}

// ---------------- K5: hinit ----------------
__global__ void k_hinit(const float* __restrict__ ctx, const float* __restrict__ Wi,
                        const float* __restrict__ bi, float* __restrict__ hinit) {
    int b = blockIdx.x; int j = threadIdx.x;  // 128
    __shared__ __align__(16) float sc[64];
    if (j < 64) sc[j] = ctx[b * 64 + j];
    __syncthreads();
    const float4* w = (const float4*)(Wi + (size_t)j * 64);
    const float4* c4 = (const float4*)sc;
    float4 a = {0, 0, 0, 0};
    #pragma unroll
    for (int q = 0; q < 16; q++) dot4(a, w[q], c4[q]);
    hinit[b * 128 + j] = bi[j] + a.x + a.y + a.z + a.w;
}

// ---------------- K6: bidirectional LSTM (precomputed input gates) ----------------
__global__ __launch_bounds__(256, 1) void k_lstm(
    const float* __restrict__ gf, const float* __restrict__ gb,
    const float* __restrict__ ctx, const float* __restrict__ hinit,
    const float* __restrict__ Wihf, const float* __restrict__ Whhf,
    const float* __restrict__ bihf, const float* __restrict__ bhhf,
    const float* __restrict__ Wihb, const float* __restrict__ Whhb,
    const float* __restrict__ bihb, const float* __restrict__ bhhb,
    float* __restrict__ out0, float* __restrict__ out1) {
    int bx = blockIdx.x; int b = bx >> 1; int dir = bx & 1; int tid = threadIdx.x;
    const float* Wih = dir ? Wihb : Wihf; const float* Whh = dir ? Whhb : Whhf;
    const float* bihp = dir ? bihb : bihf; const float* bhhp = dir ? bhhb : bhhf;
    const float* gates = dir ? gb : gf;
    float* hall = dir ? out1 : out0;
    __shared__ __align__(16) float sctx[64];
    __shared__ __align__(16) float sh[64];
    __shared__ float sg[256];
    if (tid < 64) sctx[tid] = ctx[b * 64 + tid];
    __syncthreads();
    float cterm = bihp[tid] + bhhp[tid];
    {
        const float4* wc = (const float4*)(Wih + (size_t)tid * 192 + 128);
        const float4* c4 = (const float4*)sctx;
        float4 a = {0, 0, 0, 0};
        #pragma unroll
        for (int q = 0; q < 16; q++) dot4(a, wc[q], c4[q]);
        cterm += a.x + a.y + a.z + a.w;
    }
    float4 whh[16];
    {
        const float4* w2 = (const float4*)(Whh + (size_t)tid * 64);
        #pragma unroll
        for (int q = 0; q < 16; q++) whh[q] = w2[q];
    }
    float c = 0.f;
    if (tid < 64) {
        float h0 = hinit[b * 128 + dir * 64 + tid];
        c = tanhf(h0);
        sh[tid] = h0;
        int t0 = dir ? (NT - 1) : 0;
        hall[((size_t)b * NT + t0) * NV + tid] = h0;
    }
    size_t gbb = (size_t)b * NT * 256;
    int tin0 = dir ? (NT - 1) : 0;
    float gnext = gates[gbb + (size_t)tin0 * 256 + tid];
    __syncthreads();
    for (int s = 0; s < NT - 1; s++) {
        float gcur = gnext;
        if (s + 1 < NT - 1) {
            int tin = dir ? (NT - 2 - s) : (s + 1);
            gnext = gates[gbb + (size_t)tin * 256 + tid];
        }
        {
            const float4* sh4 = (const float4*)sh;
            float4 a = {0, 0, 0, 0};
            #pragma unroll
            for (int q = 0; q < 16; q++) dot4(a, whh[q], sh4[q]);
            sg[tid] = cterm + gcur + a.x + a.y + a.z + a.w;
        }
        __syncthreads();
        if (tid < 64) {
            float gi = sg[tid], gfv = sg[64 + tid], ggv = sg[128 + tid], go = sg[192 + tid];
            c = sigm(gfv) * c + sigm(gi) * tanhf(ggv);
            float hnew = sigm(go) * tanhf(c);
            sh[tid] = hnew;
            int tout = dir ? (NT - 2 - s) : (s + 1);
            hall[((size_t)b * NT + tout) * NV + tid] = hnew;
        }
        __syncthreads();
    }
}

// ---------------- K_feat: fused per-feature MLP via bf16 MFMA ----------------
__global__ __launch_bounds__(256) void k_feat(
    const float* __restrict__ xcomp, const unsigned short* __restrict__ wbf,
    const float* __restrict__ wdiag, const float* __restrict__ bfeat,
    const float* __restrict__ Wnl1, const float* __restrict__ bnl1,
    const float* __restrict__ Wnl2, const float* __restrict__ bnl2,
    float* __restrict__ feat_out) {
    int wave = threadIdx.x >> 6; int lane = threadIdx.x & 63;
    int bt0 = blockIdx.x * 64 + wave * 16;
    int r = lane & 15, kc = lane >> 4;
    __shared__ __align__(16) unsigned short hb[4][16 * 32];
    __shared__ __align__(16) float ldsx[4][64 * 16];
    __shared__ __align__(16) float fl[4][16 * 65];
    unsigned short* hbw = hb[wave];
    float* lx = ldsx[wave];
    float* flw = fl[wave];

    short8 a0, a1;
    {
        const float* xr = xcomp + (size_t)(bt0 + r) * NV + kc * 8;
        a0 = pack8(*(const float4*)(xr), *(const float4*)(xr + 4));
        a1 = pack8(*(const float4*)(xr + 32), *(const float4*)(xr + 36));
    }
    {
        int gc0 = kc * 16;
        const float* xr2 = xcomp + (size_t)(bt0 + r) * NV + gc0;
        #pragma unroll
        for (int e = 0; e < 16; e += 4) {
            float4 p = *(const float4*)(xr2 + e);
            lx[(gc0 + e + 0) * 16 + r] = bf2f(f2bf(p.x));
            lx[(gc0 + e + 1) * 16 + r] = bf2f(f2bf(p.y));
            lx[(gc0 + e + 2) * 16 + r] = bf2f(f2bf(p.z));
            lx[(gc0 + e + 3) * 16 + r] = bf2f(f2bf(p.w));
        }
    }
    short8 wb0, wb1;
    {
        const float* w = Wnl1 + r * 32 + kc * 8;
        wb0 = pack8(*(const float4*)w, *(const float4*)(w + 4));
        const float* w2 = Wnl1 + (16 + r) * 32 + kc * 8;
        wb1 = pack8(*(const float4*)w2, *(const float4*)(w2 + 4));
    }
    float w2c0 = Wnl2[r], w2c1 = Wnl2[16 + r];
    float bn0 = bnl1[r], bn1 = bnl1[16 + r];
    float bn2 = bnl2[0];
    __builtin_amdgcn_wave_barrier();

    #pragma unroll 2
    for (int g = 0; g < 64; g++) {
        __builtin_amdgcn_wave_barrier();
        float xv[4];
        #pragma unroll
        for (int i = 0; i < 4; i++) xv[i] = lx[g * 16 + kc * 4 + i];
        float p[4] = {0.f, 0.f, 0.f, 0.f};
        #pragma unroll
        for (int f = 0; f < 2; f++) {
            int n0 = g * 32 + f * 16;
            const unsigned short* wrow = wbf + (size_t)(n0 + r) * 64;
            short8 b0 = *(const short8*)(wrow + kc * 8);
            short8 b1 = *(const short8*)(wrow + 32 + kc * 8);
            f32x4 acc = {0.f, 0.f, 0.f, 0.f};
            acc = __builtin_amdgcn_mfma_f32_16x16x32_bf16(a0, b0, acc, 0, 0, 0);
            acc = __builtin_amdgcn_mfma_f32_16x16x32_bf16(a1, b1, acc, 0, 0, 0);
            int n = n0 + r;
            float wd = wdiag[n], bs = bfeat[n];
            #pragma unroll
            for (int i = 0; i < 4; i++) {
                float h = acc[i] - xv[i] * wd + bs;
                h = fmaxf(h, 0.0f);
                hbw[(kc * 4 + i) * 32 + f * 16 + r] = f2bf(h);
            }
        }
        __builtin_amdgcn_wave_barrier();
        short8 ah = *(const short8*)(hbw + r * 32 + kc * 8);
        f32x4 z0 = {0.f, 0.f, 0.f, 0.f}, z1 = {0.f, 0.f, 0.f, 0.f};
        z0 = __builtin_amdgcn_mfma_f32_16x16x32_bf16(ah, wb0, z0, 0, 0, 0);
        z1 = __builtin_amdgcn_mfma_f32_16x16x32_bf16(ah, wb1, z1, 0, 0, 0);
        #pragma unroll
        for (int i = 0; i < 4; i++) {
            float za = fmaxf(z0[i] + bn0, 0.0f);
            float zb = fmaxf(z1[i] + bn1, 0.0f);
            p[i] = fmaf(za, w2c0, fmaf(zb, w2c1, p[i]));
        }
        #pragma unroll
        for (int m = 1; m < 16; m <<= 1) {
            #pragma unroll
            for (int i = 0; i < 4; i++) p[i] += __shfl_xor(p[i], m, 64);
        }
        if (r == 0) {
            #pragma unroll
            for (int i = 0; i < 4; i++) flw[(kc * 4 + i) * 65 + g] = p[i] + bn2;
        }
    }
    __builtin_amdgcn_wave_barrier();
    #pragma unroll
    for (int q = 0; q < 16; q++)
        feat_out[(size_t)(bt0 + q) * NV + lane] = flw[q * 65 + lane];
}

// ---------------- K7: rnn_imp = h_cat @ W_ri^T + b_ri ----------------
__global__ void k_rnnimp(const float* __restrict__ out0, const float* __restrict__ out1,
                         const float* __restrict__ Wri, const float* __restrict__ bri,
                         float* __restrict__ rnnraw) {
    int bt0 = blockIdx.x * 4;
    int tid = threadIdx.x;
    int rr = tid >> 6, v = tid & 63;
    __shared__ __align__(16) float hc[4][128];
    hc[rr][v] = out0[(size_t)(bt0 + rr) * NV + v];
    hc[rr][64 + v] = out1[(size_t)(bt0 + rr) * NV + v];
    __syncthreads();
    const float4* w = (const float4*)(Wri + (size_t)v * 128);
    const float4* h4 = (const float4*)hc[rr];
    float4 a = {0, 0, 0, 0};
    #pragma unroll
    for (int q = 0; q < 32; q++) dot4(a, w[q], h4[q]);
    rnnraw[(size_t)(bt0 + rr) * NV + v] = bri[v] + a.x + a.y + a.z + a.w;
}

// ---------------- K8: beta fusion + scale + write all 3 outputs ----------------
__global__ void k_final(const float* __restrict__ rnnraw, const float* __restrict__ gam,
                        const float* __restrict__ masks, const float* __restrict__ Wfu,
                        const float* __restrict__ bfu, const float* __restrict__ mmn_ws,
                        const float* __restrict__ minv, float* __restrict__ out0,
                        float* __restrict__ out1, float* __restrict__ out2) {
    int bt0 = blockIdx.x * 4; int tid = threadIdx.x;
    int rr = tid >> 6, v = tid & 63;
    __shared__ __align__(16) float gm[4][128];
    size_t row = (size_t)(bt0 + rr) * NV;
    gm[rr][v] = gam[row + v];
    gm[rr][64 + v] = masks[row + v];
    __syncthreads();
    const float4* w = (const float4*)(Wfu + (size_t)v * 128);
    const float4* x4 = (const float4*)gm[rr];
    float4 a = {0, 0, 0, 0};
    #pragma unroll
    for (int q = 0; q < 32; q++) dot4(a, w[q], x4[q]);
    float beta = sigm(bfu[v] + a.x + a.y + a.z + a.w);
    size_t idx = row + v;
    float rn = rnnraw[idx];
    float ft = out2[idx];
    float fin = beta * ft + (1.0f - beta) * rn;
    int b = (bt0 + rr) >> 8;
    float mm = mmn_ws[b * NV + v], mn = minv[b * NV + v];
    out0[idx] = fmaf(rn, mm, mn);
    out1[idx] = fmaf(ft, mm, mn);
    out2[idx] = fmaf(fin, mm, mn);
}

extern "C" void kernel_launch(void* const* d_in, const int* in_sizes, int n_in,
                              void* d_out, int out_size, void* d_ws, size_t ws_size,
                              hipStream_t stream) {
    const int*   lengths  = (const int*)d_in[0];
    const float* values   = (const float*)d_in[1];
    const float* masks    = (const float*)d_in[2];
    const float* deltas   = (const float*)d_in[3];
    const float* min_vals = (const float*)d_in[4];
    const float* max_vals = (const float*)d_in[5];
    const float* W_decay  = (const float*)d_in[6];
    const float* b_decay  = (const float*)d_in[7];
    const float* W_feat   = (const float*)d_in[8];
    const float* b_feat   = (const float*)d_in[9];
    const float* W_nl1    = (const float*)d_in[10];
    const float* b_nl1    = (const float*)d_in[11];
    const float* W_nl2    = (const float*)d_in[12];
    const float* b_nl2    = (const float*)d_in[13];
    const float* Wc1      = (const float*)d_in[14];
    const float* bc1      = (const float*)d_in[15];
    const float* Wc2      = (const float*)d_in[16];
    const float* bc2      = (const float*)d_in[17];
    const float* W_ih_g   = (const float*)d_in[18];
    const float* W_hh_g   = (const float*)d_in[19];
    const float* b_ih_g   = (const float*)d_in[20];
    const float* b_hh_g   = (const float*)d_in[21];
    const float* W_init   = (const float*)d_in[22];
    const float* b_init   = (const float*)d_in[23];
    const float* W_ih_f   = (const float*)d_in[24];
    const float* W_hh_f   = (const float*)d_in[25];
    const float* b_ih_f   = (const float*)d_in[26];
    const float* b_hh_f   = (const float*)d_in[27];
    const float* W_ih_b   = (const float*)d_in[28];
    const float* W_hh_b   = (const float*)d_in[29];
    const float* b_ih_b   = (const float*)d_in[30];
    const float* b_hh_b   = (const float*)d_in[31];
    const float* W_ri     = (const float*)d_in[32];
    const float* b_ri     = (const float*)d_in[33];
    const float* W_fu     = (const float*)d_in[34];
    const float* b_fu     = (const float*)d_in[35];

    float* ws = (float*)d_ws;
    float* xcomp  = ws;                     // 2097152
    float* gam    = ws + 2097152;           // 2097152
    float* rnnraw = ws + 4194304;           // 2097152
    float* stats  = ws + 6291456;           // 32768
    float* mmn    = ws + 6324224;           // 8192
    float* nmeans = ws + 6332416;           // 8192
    float* ctx    = ws + 6340608;           // 8192
    float* hinit  = ws + 6348800;           // 16384
    unsigned short* wbf = (unsigned short*)(ws + 6365184);  // 131072 ushorts
    float* wdiag  = ws + 6430720;           // 2048
    unsigned short* wgf = (unsigned short*)(ws + 6432768); // 32768 ushorts
    unsigned short* wgb = (unsigned short*)(ws + 6449152); // 32768 ushorts
    unsigned short* wgg = (unsigned short*)(ws + 6465536); // 12288 ushorts
    float* gates_f = ws + 6471680;          // 8388608
    float* gates_b = ws + 14860288;         // 8388608
    float* gates_g = ws + 23248896;         // 3145728  (total ~105.6 MB)

    float* out0 = (float*)d_out;
    float* out1 = out0 + NBTV;
    float* out2 = out0 + 2 * NBTV;

    k_conv<<<512, 256, 0, stream>>>(W_feat, W_ih_f, W_ih_b, W_ih_g, wbf, wdiag, wgf, wgb, wgg);
    k_stats<<<NB, 64, 0, stream>>>(lengths, values, masks, min_vals, max_vals, stats, mmn, nmeans);
    k_fill<<<NB, 64, 0, stream>>>(values, masks, deltas, min_vals, W_decay, b_decay, mmn, nmeans, xcomp, gam);
    k_gates<<<NBT / 64, 256, 0, stream>>>(xcomp, masks, wgf, wgb, wgg, gates_f, gates_b, gates_g);
    k_feat<<<NBT / 64, 256, 0, stream>>>(xcomp, wbf, wdiag, b_feat, W_nl1, b_nl1, W_nl2, b_nl2, out2);
    k_ctxmlp<<<NB, 64, 0, stream>>>(stats, Wc1, bc1, Wc2, bc2, ctx);
    k_gru<<<NB, 128, 0, stream>>>(gates_g, lengths, W_hh_g, b_ih_g, b_hh_g, ctx);
    k_hinit<<<NB, 128, 0, stream>>>(ctx, W_init, b_init, hinit);
    k_lstm<<<2 * NB, 256, 0, stream>>>(gates_f, gates_b, ctx, hinit,
                                       W_ih_f, W_hh_f, b_ih_f, b_hh_f,
                                       W_ih_b, W_hh_b, b_ih_b, b_hh_b, out0, out1);
    k_rnnimp<<<NBT / 4, 256, 0, stream>>>(out0, out1, W_ri, b_ri, rnnraw);
    k_final<<<NBT / 4, 256, 0, stream>>>(rnnraw, gam, masks, W_fu, b_fu, mmn, min_vals, out0, out1, out2);
}